// Round 1
// baseline (292.670 us; speedup 1.0000x reference)
//
#include <hip/hip_runtime.h>
#include <stdint.h>

#define BB 16
#define CC 256
#define PP 4096
#define CPG 32

typedef __attribute__((ext_vector_type(4))) float f32x4;
typedef __attribute__((ext_vector_type(8))) short bf16x8;

static __device__ __forceinline__ float bf2f(unsigned short u) {
    union { uint32_t i; float f; } w; w.i = ((uint32_t)u) << 16; return w.f;
}
static __device__ __forceinline__ unsigned short f2bf(float f) {
    union { float f; uint32_t i; } w; w.f = f;
    uint32_t u = w.i;
    uint32_t r = u + 0x7FFFu + ((u >> 16) & 1u);
    return (unsigned short)(r >> 16);
}

// ---------------- GroupNorm stats (two stage) ----------------
__global__ void gn_partial_k(const float* __restrict__ x, float* __restrict__ part) {
    int bg = blockIdx.x >> 2, chunk = blockIdx.x & 3;
    const f32x4* v = (const f32x4*)(x + (size_t)bg * (CPG * PP) + (size_t)chunk * (CPG * PP / 4));
    float s = 0.f, ss = 0.f;
    for (int i = threadIdx.x; i < (CPG * PP / 4 / 4); i += 256) {
        f32x4 t = v[i];
        s  += t.x + t.y + t.z + t.w;
        ss += t.x * t.x + t.y * t.y + t.z * t.z + t.w * t.w;
    }
    for (int off = 32; off > 0; off >>= 1) {
        s  += __shfl_down(s, off);
        ss += __shfl_down(ss, off);
    }
    __shared__ float ls[4], lss[4];
    int wv = threadIdx.x >> 6;
    if ((threadIdx.x & 63) == 0) { ls[wv] = s; lss[wv] = ss; }
    __syncthreads();
    if (threadIdx.x == 0) {
        part[blockIdx.x * 2 + 0] = ls[0] + ls[1] + ls[2] + ls[3];
        part[blockIdx.x * 2 + 1] = lss[0] + lss[1] + lss[2] + lss[3];
    }
}

__global__ void gn_final_k(const float* __restrict__ part, const float* __restrict__ nw,
                           const float* __restrict__ nb, float* __restrict__ a_s,
                           float* __restrict__ b_s) {
    int bg = threadIdx.x;  // 0..127, block of 128
    float S = 0.f, SS = 0.f;
    for (int i = 0; i < 4; i++) { S += part[(bg * 4 + i) * 2]; SS += part[(bg * 4 + i) * 2 + 1]; }
    const float inv = 1.0f / (float)(CPG * PP);
    float mean = S * inv;
    float var = SS * inv - mean * mean;
    float rstd = rsqrtf(var + 1e-5f);
    int b = bg >> 3, g = bg & 7;
    for (int j = 0; j < CPG; j++) {
        int c = g * CPG + j;
        float w = nw[c];
        a_s[b * CC + c] = rstd * w;
        b_s[b * CC + c] = nb[c] - mean * rstd * w;
    }
}

// ---------------- weight fp32 -> bf16 ----------------
__global__ void cvt_bf16_k(const float* __restrict__ in, unsigned short* __restrict__ out, int n) {
    int i = blockIdx.x * 256 + threadIdx.x;
    if (i < n) out[i] = f2bf(in[i]);
}

// ---------------- fused normalize + transpose: xnT[b][p][c] bf16 ----------------
__global__ void xnt_k(const float* __restrict__ x, const float* __restrict__ a_s,
                      const float* __restrict__ b_s, unsigned short* __restrict__ xnT) {
    int pt = blockIdx.x & 63, ct = (blockIdx.x >> 6) & 3, b = blockIdx.x >> 8;
    int c0 = ct * 64, p0 = pt * 64;
    __shared__ unsigned short T[64][66];
    int t = threadIdx.x;
    int cl = t >> 4, pl4 = (t & 15) * 4;
    for (int i = 0; i < 4; i++) {
        int c = c0 + i * 16 + cl;
        float a = a_s[b * CC + c], sh = b_s[b * CC + c];
        f32x4 v = *(const f32x4*)(x + ((size_t)b * CC + c) * PP + p0 + pl4);
        T[i * 16 + cl][pl4 + 0] = f2bf(a * v.x + sh);
        T[i * 16 + cl][pl4 + 1] = f2bf(a * v.y + sh);
        T[i * 16 + cl][pl4 + 2] = f2bf(a * v.z + sh);
        T[i * 16 + cl][pl4 + 3] = f2bf(a * v.w + sh);
    }
    __syncthreads();
    int pl = t >> 2, c16 = (t & 3) * 16;
    union { unsigned short h[16]; uint4 u[2]; } buf;
    for (int j = 0; j < 16; j++) buf.h[j] = T[c16 + j][pl];
    unsigned short* dst = xnT + ((size_t)b * PP + p0 + pl) * CC + c0 + c16;
    *(uint4*)dst       = buf.u[0];
    *(uint4*)(dst + 8) = buf.u[1];
}

// ---------------- shared GEMM core: 128x128 tile, K=256, bf16 MFMA ----------------
// A: [>=o0+128][256] row-major (k contiguous).  B-source: rows are the N dim,
// k contiguous (i.e. already transposed), [>=p0+128][256].
static __device__ __forceinline__ void gemm_core(const unsigned short* __restrict__ Aglob,
                                                 const unsigned short* __restrict__ Bglob,
                                                 f32x4 (&acc)[4][4]) {
    __shared__ unsigned short As[128][32];   // no pad: 64B row stride -> dense 1KiB frag reads
    __shared__ unsigned short Bs[128][32];
    int t = threadIdx.x;
    int lane = t & 63, wave = t >> 6;
    int wm = wave >> 1, wn = wave & 1;
    int lr = lane & 15, lq = lane >> 4;
    int srow = t >> 2, sk8 = (t & 3) * 8;
    for (int mi = 0; mi < 4; mi++)
        for (int ni = 0; ni < 4; ni++) {
            acc[mi][ni][0] = 0.f; acc[mi][ni][1] = 0.f;
            acc[mi][ni][2] = 0.f; acc[mi][ni][3] = 0.f;
        }
    for (int k0 = 0; k0 < 256; k0 += 32) {
        uint4 av0 = *(const uint4*)(Aglob + (size_t)srow * 256 + k0 + sk8);
        uint4 av1 = *(const uint4*)(Aglob + (size_t)(srow + 64) * 256 + k0 + sk8);
        uint4 bv0 = *(const uint4*)(Bglob + (size_t)srow * 256 + k0 + sk8);
        uint4 bv1 = *(const uint4*)(Bglob + (size_t)(srow + 64) * 256 + k0 + sk8);
        __syncthreads();
        *(uint4*)&As[srow][sk8]      = av0;
        *(uint4*)&As[srow + 64][sk8] = av1;
        *(uint4*)&Bs[srow][sk8]      = bv0;
        *(uint4*)&Bs[srow + 64][sk8] = bv1;
        __syncthreads();
        bf16x8 af[4], bfr[4];
        for (int mi = 0; mi < 4; mi++) af[mi]  = *(const bf16x8*)&As[wm * 64 + mi * 16 + lr][lq * 8];
        for (int ni = 0; ni < 4; ni++) bfr[ni] = *(const bf16x8*)&Bs[wn * 64 + ni * 16 + lr][lq * 8];
        for (int mi = 0; mi < 4; mi++)
            for (int ni = 0; ni < 4; ni++)
                acc[mi][ni] = __builtin_amdgcn_mfma_f32_16x16x32_bf16(af[mi], bfr[ni], acc[mi][ni], 0, 0, 0);
    }
}

// ---------------- QKV GEMM: writes q,k channel-major; v transposed ----------------
__global__ __launch_bounds__(256) void qkv_gemm_k(const unsigned short* __restrict__ Wq,
                                                  const unsigned short* __restrict__ xnT,
                                                  const float* __restrict__ qkv_b,
                                                  unsigned short* __restrict__ qk,
                                                  unsigned short* __restrict__ vT) {
    int nt = blockIdx.x & 31;
    int rest = blockIdx.x >> 5;
    int mt = rest % 6;
    int b  = rest / 6;
    int o0 = mt * 128, p0 = nt * 128;
    f32x4 acc[4][4];
    gemm_core(Wq + (size_t)o0 * 256, xnT + ((size_t)b * PP + p0) * 256, acc);
    int t = threadIdx.x, lane = t & 63, wave = t >> 6;
    int wm = wave >> 1, wn = wave & 1, lr = lane & 15, lq = lane >> 4;
    if (o0 < 512) {
        for (int mi = 0; mi < 4; mi++) {
            int ob = o0 + wm * 64 + mi * 16 + lq * 4;
            for (int ni = 0; ni < 4; ni++) {
                int p = p0 + wn * 64 + ni * 16 + lr;
                for (int r = 0; r < 4; r++) {
                    int o = ob + r;
                    qk[((size_t)b * 512 + o) * PP + p] = f2bf(acc[mi][ni][r] + qkv_b[o]);
                }
            }
        }
    } else {
        for (int mi = 0; mi < 4; mi++) {
            int cb = (o0 - 512) + wm * 64 + mi * 16 + lq * 4;
            for (int ni = 0; ni < 4; ni++) {
                int p = p0 + wn * 64 + ni * 16 + lr;
                for (int r = 0; r < 4; r++) {
                    int c = cb + r;
                    vT[((size_t)b * PP + p) * CC + c] = f2bf(acc[mi][ni][r] + qkv_b[512 + c]);
                }
            }
        }
    }
}

// ---------------- scores: attn[b][hh][n][m], softmax over m ----------------
__global__ void scores_k(const unsigned short* __restrict__ qk, float* __restrict__ attn) {
    int b = blockIdx.x >> 6, hh = blockIdx.x & 63;
    int t = threadIdx.x, lane = t & 63, wave = t >> 6;
    float acc[16];
    for (int i = 0; i < 16; i++) acc[i] = 0.f;
    const unsigned short* qb = qk + (size_t)b * 512 * PP + (size_t)hh * PP;
    for (int p = t * 4; p < PP; p += 1024) {
        float qv[4][4], kv[4][4];
        for (int n = 0; n < 4; n++) {
            ushort4 u = *(const ushort4*)(qb + (size_t)n * 64 * PP + p);
            qv[n][0] = bf2f(u.x); qv[n][1] = bf2f(u.y); qv[n][2] = bf2f(u.z); qv[n][3] = bf2f(u.w);
        }
        for (int m = 0; m < 4; m++) {
            ushort4 u = *(const ushort4*)(qb + (size_t)(256 + m * 64) * PP + p);
            kv[m][0] = bf2f(u.x); kv[m][1] = bf2f(u.y); kv[m][2] = bf2f(u.z); kv[m][3] = bf2f(u.w);
        }
        for (int n = 0; n < 4; n++)
            for (int m = 0; m < 4; m++)
                acc[n * 4 + m] += qv[n][0] * kv[m][0] + qv[n][1] * kv[m][1] +
                                  qv[n][2] * kv[m][2] + qv[n][3] * kv[m][3];
    }
    __shared__ float red[4][16];
    __shared__ float sfin[16];
    for (int i = 0; i < 16; i++) {
        float v = acc[i];
        for (int off = 32; off > 0; off >>= 1) v += __shfl_down(v, off);
        if (lane == 0) red[wave][i] = v;
    }
    __syncthreads();
    if (t < 16) sfin[t] = red[0][t] + red[1][t] + red[2][t] + red[3][t];
    __syncthreads();
    if (t < 4) {
        float v0 = sfin[t * 4 + 0] * 0.125f, v1 = sfin[t * 4 + 1] * 0.125f;
        float v2 = sfin[t * 4 + 2] * 0.125f, v3 = sfin[t * 4 + 3] * 0.125f;
        float mx = fmaxf(fmaxf(v0, v1), fmaxf(v2, v3));
        float e0 = expf(v0 - mx), e1 = expf(v1 - mx), e2 = expf(v2 - mx), e3 = expf(v3 - mx);
        float inv = 1.0f / (e0 + e1 + e2 + e3);
        float* dst = attn + ((size_t)(b * 64 + hh) * 4 + t) * 4;
        dst[0] = e0 * inv; dst[1] = e1 * inv; dst[2] = e2 * inv; dst[3] = e3 * inv;
    }
}

// ---------------- fold attn into proj weights: Wp[b][o][m*64+hh] bf16 ----------------
__global__ void make_wp_k(const float* __restrict__ proj_w, const float* __restrict__ attn,
                          unsigned short* __restrict__ Wp) {
    int t = threadIdx.x;
    int o = blockIdx.x & 255, b = blockIdx.x >> 8;
    int m = t >> 6, hh = t & 63;
    float s = 0.f;
    for (int n = 0; n < 4; n++)
        s += proj_w[o * 256 + n * 64 + hh] * attn[((size_t)(b * 64 + hh) * 4 + n) * 4 + m];
    Wp[((size_t)b * 256 + o) * 256 + t] = f2bf(s);
}

// ---------------- final GEMM: out = Wp_b @ v + proj_b + x ----------------
__global__ __launch_bounds__(256) void final_gemm_k(const unsigned short* __restrict__ Wp,
                                                    const unsigned short* __restrict__ vT,
                                                    const float* __restrict__ proj_b,
                                                    const float* __restrict__ x,
                                                    float* __restrict__ out) {
    int nt = blockIdx.x & 31;
    int rest = blockIdx.x >> 5;
    int mt = rest & 1;
    int b  = rest >> 1;
    int o0 = mt * 128, p0 = nt * 128;
    f32x4 acc[4][4];
    gemm_core(Wp + ((size_t)b * 256 + o0) * 256, vT + ((size_t)b * PP + p0) * 256, acc);
    int t = threadIdx.x, lane = t & 63, wave = t >> 6;
    int wm = wave >> 1, wn = wave & 1, lr = lane & 15, lq = lane >> 4;
    for (int mi = 0; mi < 4; mi++) {
        int ob = o0 + wm * 64 + mi * 16 + lq * 4;
        for (int ni = 0; ni < 4; ni++) {
            int p = p0 + wn * 64 + ni * 16 + lr;
            for (int r = 0; r < 4; r++) {
                int o = ob + r;
                size_t idx = ((size_t)b * CC + o) * PP + p;
                out[idx] = acc[mi][ni][r] + proj_b[o] + x[idx];
            }
        }
    }
}

extern "C" void kernel_launch(void* const* d_in, const int* in_sizes, int n_in,
                              void* d_out, int out_size, void* d_ws, size_t ws_size,
                              hipStream_t stream) {
    const float* x      = (const float*)d_in[0];
    const float* norm_w = (const float*)d_in[1];
    const float* norm_b = (const float*)d_in[2];
    const float* qkv_w  = (const float*)d_in[3];
    const float* qkv_b  = (const float*)d_in[4];
    const float* proj_w = (const float*)d_in[5];
    const float* proj_b = (const float*)d_in[6];
    float* out = (float*)d_out;

    char* ws = (char*)d_ws;
    size_t off = 0;
    auto alloc = [&](size_t bytes) {
        void* p = ws + off;
        off += (bytes + 255) & ~(size_t)255;
        return p;
    };
    float* part = (float*)alloc(512 * 2 * sizeof(float));
    float* a_s  = (float*)alloc(BB * CC * sizeof(float));
    float* b_s  = (float*)alloc(BB * CC * sizeof(float));
    float* attn = (float*)alloc((size_t)BB * 64 * 16 * sizeof(float));
    unsigned short* Wqb = (unsigned short*)alloc((size_t)768 * 256 * 2);
    unsigned short* Wp  = (unsigned short*)alloc((size_t)BB * 256 * 256 * 2);
    unsigned short* xnT = (unsigned short*)alloc((size_t)BB * PP * CC * 2);
    unsigned short* qk  = (unsigned short*)alloc((size_t)BB * 512 * PP * 2);
    unsigned short* vT  = (unsigned short*)alloc((size_t)BB * PP * CC * 2);

    gn_partial_k<<<512, 256, 0, stream>>>(x, part);
    gn_final_k<<<1, 128, 0, stream>>>(part, norm_w, norm_b, a_s, b_s);
    cvt_bf16_k<<<768, 256, 0, stream>>>(qkv_w, Wqb, 768 * 256);
    xnt_k<<<4096, 256, 0, stream>>>(x, a_s, b_s, xnT);
    qkv_gemm_k<<<16 * 6 * 32, 256, 0, stream>>>(Wqb, xnT, qkv_b, qk, vT);
    scores_k<<<16 * 64, 256, 0, stream>>>(qk, attn);
    make_wp_k<<<16 * 256, 256, 0, stream>>>(proj_w, attn, Wp);
    final_gemm_k<<<16 * 2 * 32, 256, 0, stream>>>(Wp, vT, proj_b, x, out);
}

// Round 2
// 283.495 us; speedup vs baseline: 1.0324x; 1.0324x over previous
//
#include <hip/hip_runtime.h>
#include <stdint.h>

#define BB 16
#define CC 256
#define PP 4096
#define CPG 32

typedef __attribute__((ext_vector_type(4))) float f32x4;
typedef __attribute__((ext_vector_type(8))) short bf16x8;

static __device__ __forceinline__ float bf2f(unsigned short u) {
    union { uint32_t i; float f; } w; w.i = ((uint32_t)u) << 16; return w.f;
}
static __device__ __forceinline__ unsigned short f2bf(float f) {
    union { float f; uint32_t i; } w; w.f = f;
    uint32_t u = w.i;
    uint32_t r = u + 0x7FFFu + ((u >> 16) & 1u);
    return (unsigned short)(r >> 16);
}

// async global -> LDS, 16 bytes per lane
static __device__ __forceinline__ void gl2lds16(const void* g, void* l) {
    __builtin_amdgcn_global_load_lds(
        (const __attribute__((address_space(1))) void*)g,
        (__attribute__((address_space(3))) void*)l, 16, 0, 0);
}

// ---------------- GroupNorm stats (two stage) ----------------
__global__ void gn_partial_k(const float* __restrict__ x, float* __restrict__ part) {
    int bg = blockIdx.x >> 2, chunk = blockIdx.x & 3;
    const f32x4* v = (const f32x4*)(x + (size_t)bg * (CPG * PP) + (size_t)chunk * (CPG * PP / 4));
    float s = 0.f, ss = 0.f;
    for (int i = threadIdx.x; i < (CPG * PP / 4 / 4); i += 256) {
        f32x4 t = v[i];
        s  += t.x + t.y + t.z + t.w;
        ss += t.x * t.x + t.y * t.y + t.z * t.z + t.w * t.w;
    }
    for (int off = 32; off > 0; off >>= 1) {
        s  += __shfl_down(s, off);
        ss += __shfl_down(ss, off);
    }
    __shared__ float ls[4], lss[4];
    int wv = threadIdx.x >> 6;
    if ((threadIdx.x & 63) == 0) { ls[wv] = s; lss[wv] = ss; }
    __syncthreads();
    if (threadIdx.x == 0) {
        part[blockIdx.x * 2 + 0] = ls[0] + ls[1] + ls[2] + ls[3];
        part[blockIdx.x * 2 + 1] = lss[0] + lss[1] + lss[2] + lss[3];
    }
}

__global__ void gn_final_k(const float* __restrict__ part, const float* __restrict__ nw,
                           const float* __restrict__ nb, float* __restrict__ a_s,
                           float* __restrict__ b_s) {
    int bg = threadIdx.x;  // 0..127
    float S = 0.f, SS = 0.f;
    for (int i = 0; i < 4; i++) { S += part[(bg * 4 + i) * 2]; SS += part[(bg * 4 + i) * 2 + 1]; }
    const float inv = 1.0f / (float)(CPG * PP);
    float mean = S * inv;
    float var = SS * inv - mean * mean;
    float rstd = rsqrtf(var + 1e-5f);
    int b = bg >> 3, g = bg & 7;
    for (int j = 0; j < CPG; j++) {
        int c = g * CPG + j;
        float w = nw[c];
        a_s[b * CC + c] = rstd * w;
        b_s[b * CC + c] = nb[c] - mean * rstd * w;
    }
}

// ---------------- weight fp32 -> bf16 ----------------
__global__ void cvt_bf16_k(const float* __restrict__ in, unsigned short* __restrict__ out, int n) {
    int i = blockIdx.x * 256 + threadIdx.x;
    if (i < n) out[i] = f2bf(in[i]);
}

// ---------------- fused normalize + transpose: xnT[b][p][c] bf16 ----------------
__global__ void xnt_k(const float* __restrict__ x, const float* __restrict__ a_s,
                      const float* __restrict__ b_s, unsigned short* __restrict__ xnT) {
    int pt = blockIdx.x & 63, ct = (blockIdx.x >> 6) & 3, b = blockIdx.x >> 8;
    int c0 = ct * 64, p0 = pt * 64;
    __shared__ unsigned short T[64][66];
    int t = threadIdx.x;
    int cl = t >> 4, pl4 = (t & 15) * 4;
    for (int i = 0; i < 4; i++) {
        int c = c0 + i * 16 + cl;
        float a = a_s[b * CC + c], sh = b_s[b * CC + c];
        f32x4 v = *(const f32x4*)(x + ((size_t)b * CC + c) * PP + p0 + pl4);
        T[i * 16 + cl][pl4 + 0] = f2bf(a * v.x + sh);
        T[i * 16 + cl][pl4 + 1] = f2bf(a * v.y + sh);
        T[i * 16 + cl][pl4 + 2] = f2bf(a * v.z + sh);
        T[i * 16 + cl][pl4 + 3] = f2bf(a * v.w + sh);
    }
    __syncthreads();
    int pl = t >> 2, c16 = (t & 3) * 16;
    union { unsigned short h[16]; uint4 u[2]; } buf;
    for (int j = 0; j < 16; j++) buf.h[j] = T[c16 + j][pl];
    unsigned short* dst = xnT + ((size_t)b * PP + p0 + pl) * CC + c0 + c16;
    *(uint4*)dst       = buf.u[0];
    *(uint4*)(dst + 8) = buf.u[1];
}

// ---------------- GEMM core: 128x128 tile, K=256, bf16 MFMA, global_load_lds ----
// Rg rows (k-contiguous, stride 256) map to the MFMA D *row* (per-lane r index).
// Cg rows map to the D *col* (lane lr index). Both staged via async DMA.
static __device__ __forceinline__ void gemm_core(const unsigned short* __restrict__ Rg,
                                                 const unsigned short* __restrict__ Cg,
                                                 f32x4 (&acc)[4][4]) {
    __shared__ unsigned short Rs[128][32];   // 64B row stride -> dense 1KiB frag reads
    __shared__ unsigned short Cs[128][32];
    int t = threadIdx.x;
    int lane = t & 63, wave = t >> 6;
    int wm = wave >> 1, wn = wave & 1;
    int lr = lane & 15, lq = lane >> 4;
    int srow = t >> 2, sk8 = (t & 3) * 8;
    for (int mi = 0; mi < 4; mi++)
        for (int ni = 0; ni < 4; ni++) {
            acc[mi][ni][0] = 0.f; acc[mi][ni][1] = 0.f;
            acc[mi][ni][2] = 0.f; acc[mi][ni][3] = 0.f;
        }
    const unsigned short* gr0 = Rg + (size_t)srow * 256 + sk8;
    const unsigned short* gr1 = gr0 + (size_t)64 * 256;
    const unsigned short* gc0 = Cg + (size_t)srow * 256 + sk8;
    const unsigned short* gc1 = gc0 + (size_t)64 * 256;
    char* lr0 = (char*)&Rs[0][0] + t * 16;
    char* lr1 = lr0 + 4096;
    char* lc0 = (char*)&Cs[0][0] + t * 16;
    char* lc1 = lc0 + 4096;
    for (int k0 = 0; k0 < 256; k0 += 32) {
        __syncthreads();                 // previous tile's reads complete
        gl2lds16(gr0 + k0, lr0);
        gl2lds16(gr1 + k0, lr1);
        gl2lds16(gc0 + k0, lc0);
        gl2lds16(gc1 + k0, lc1);
        __syncthreads();                 // drains vmcnt -> DMA data visible
        bf16x8 af[4], bfr[4];
        for (int mi = 0; mi < 4; mi++) af[mi]  = *(const bf16x8*)&Rs[wm * 64 + mi * 16 + lr][lq * 8];
        for (int ni = 0; ni < 4; ni++) bfr[ni] = *(const bf16x8*)&Cs[wn * 64 + ni * 16 + lr][lq * 8];
        for (int mi = 0; mi < 4; mi++)
            for (int ni = 0; ni < 4; ni++)
                acc[mi][ni] = __builtin_amdgcn_mfma_f32_16x16x32_bf16(af[mi], bfr[ni], acc[mi][ni], 0, 0, 0);
    }
}

// ---------------- QKV GEMM ----------------
// mt<4 : q/k rows o0=mt*128      -> R = xnT (p on r-index), C = W   ; qk[(b,o,p)] packed p
// mt>=4: v rows                  -> R = W   (c on r-index), C = xnT ; vT[(b,p,c)] packed c
__global__ __launch_bounds__(256) void qkv_gemm_k(const unsigned short* __restrict__ Wq,
                                                  const unsigned short* __restrict__ xnT,
                                                  const float* __restrict__ qkv_b,
                                                  unsigned short* __restrict__ qk,
                                                  unsigned short* __restrict__ vT) {
    int nt = blockIdx.x & 31;
    int rest = blockIdx.x >> 5;
    int mt = rest % 6;
    int b  = rest / 6;
    int o0 = mt * 128, p0 = nt * 128;
    int t = threadIdx.x, lane = t & 63, wave = t >> 6;
    int wm = wave >> 1, wn = wave & 1, lr = lane & 15, lq = lane >> 4;
    f32x4 acc[4][4];
    if (o0 < 512) {
        gemm_core(xnT + ((size_t)b * PP + p0) * 256, Wq + (size_t)o0 * 256, acc);
        for (int mi = 0; mi < 4; mi++) {
            int p4 = p0 + wm * 64 + mi * 16 + lq * 4;
            for (int ni = 0; ni < 4; ni++) {
                int o = o0 + wn * 64 + ni * 16 + lr;
                float bias = qkv_b[o];
                ushort4 u;
                u.x = f2bf(acc[mi][ni][0] + bias);
                u.y = f2bf(acc[mi][ni][1] + bias);
                u.z = f2bf(acc[mi][ni][2] + bias);
                u.w = f2bf(acc[mi][ni][3] + bias);
                *(ushort4*)(qk + ((size_t)b * 512 + o) * PP + p4) = u;
            }
        }
    } else {
        gemm_core(Wq + (size_t)o0 * 256, xnT + ((size_t)b * PP + p0) * 256, acc);
        for (int mi = 0; mi < 4; mi++) {
            int c4 = (o0 - 512) + wm * 64 + mi * 16 + lq * 4;
            for (int ni = 0; ni < 4; ni++) {
                int p = p0 + wn * 64 + ni * 16 + lr;
                ushort4 u;
                u.x = f2bf(acc[mi][ni][0] + qkv_b[512 + c4 + 0]);
                u.y = f2bf(acc[mi][ni][1] + qkv_b[512 + c4 + 1]);
                u.z = f2bf(acc[mi][ni][2] + qkv_b[512 + c4 + 2]);
                u.w = f2bf(acc[mi][ni][3] + qkv_b[512 + c4 + 3]);
                *(ushort4*)(vT + ((size_t)b * PP + p) * CC + c4) = u;
            }
        }
    }
}

// ---------------- scores: attn[b][hh][n][m], softmax over m ----------------
__global__ void scores_k(const unsigned short* __restrict__ qk, float* __restrict__ attn) {
    int b = blockIdx.x >> 6, hh = blockIdx.x & 63;
    int t = threadIdx.x, lane = t & 63, wave = t >> 6;
    float acc[16];
    for (int i = 0; i < 16; i++) acc[i] = 0.f;
    const unsigned short* qb = qk + (size_t)b * 512 * PP + (size_t)hh * PP;
    for (int p = t * 8; p < PP; p += 2048) {
        float qv[4][8], kv[4][8];
        for (int n = 0; n < 4; n++) {
            uint4 u = *(const uint4*)(qb + (size_t)n * 64 * PP + p);
            const unsigned short* hs = (const unsigned short*)&u;
            for (int j = 0; j < 8; j++) qv[n][j] = bf2f(hs[j]);
        }
        for (int m = 0; m < 4; m++) {
            uint4 u = *(const uint4*)(qb + (size_t)(256 + m * 64) * PP + p);
            const unsigned short* hs = (const unsigned short*)&u;
            for (int j = 0; j < 8; j++) kv[m][j] = bf2f(hs[j]);
        }
        for (int n = 0; n < 4; n++)
            for (int m = 0; m < 4; m++) {
                float s = 0.f;
                for (int j = 0; j < 8; j++) s += qv[n][j] * kv[m][j];
                acc[n * 4 + m] += s;
            }
    }
    __shared__ float red[4][16];
    __shared__ float sfin[16];
    for (int i = 0; i < 16; i++) {
        float v = acc[i];
        for (int off = 32; off > 0; off >>= 1) v += __shfl_down(v, off);
        if (lane == 0) red[wave][i] = v;
    }
    __syncthreads();
    if (t < 16) sfin[t] = red[0][t] + red[1][t] + red[2][t] + red[3][t];
    __syncthreads();
    if (t < 4) {
        float v0 = sfin[t * 4 + 0] * 0.125f, v1 = sfin[t * 4 + 1] * 0.125f;
        float v2 = sfin[t * 4 + 2] * 0.125f, v3 = sfin[t * 4 + 3] * 0.125f;
        float mx = fmaxf(fmaxf(v0, v1), fmaxf(v2, v3));
        float e0 = expf(v0 - mx), e1 = expf(v1 - mx), e2 = expf(v2 - mx), e3 = expf(v3 - mx);
        float inv = 1.0f / (e0 + e1 + e2 + e3);
        float* dst = attn + ((size_t)(b * 64 + hh) * 4 + t) * 4;
        dst[0] = e0 * inv; dst[1] = e1 * inv; dst[2] = e2 * inv; dst[3] = e3 * inv;
    }
}

// ---------------- fold attn into proj weights: Wp[b][o][m*64+hh] bf16 ----------------
__global__ void make_wp_k(const float* __restrict__ proj_w, const float* __restrict__ attn,
                          unsigned short* __restrict__ Wp) {
    int t = threadIdx.x;
    int o = blockIdx.x & 255, b = blockIdx.x >> 8;
    int m = t >> 6, hh = t & 63;
    float s = 0.f;
    for (int n = 0; n < 4; n++)
        s += proj_w[o * 256 + n * 64 + hh] * attn[((size_t)(b * 64 + hh) * 4 + n) * 4 + m];
    Wp[((size_t)b * 256 + o) * 256 + t] = f2bf(s);
}

// ---------------- final GEMM: out = Wp_b @ v + proj_b + x (p on r-index) ----------
__global__ __launch_bounds__(256) void final_gemm_k(const unsigned short* __restrict__ Wp,
                                                    const unsigned short* __restrict__ vT,
                                                    const float* __restrict__ proj_b,
                                                    const float* __restrict__ x,
                                                    float* __restrict__ out) {
    int nt = blockIdx.x & 31;
    int rest = blockIdx.x >> 5;
    int mt = rest & 1;
    int b  = rest >> 1;
    int o0 = mt * 128, p0 = nt * 128;
    f32x4 acc[4][4];
    gemm_core(vT + ((size_t)b * PP + p0) * 256, Wp + ((size_t)b * 256 + o0) * 256, acc);
    int t = threadIdx.x, lane = t & 63, wave = t >> 6;
    int wm = wave >> 1, wn = wave & 1, lr = lane & 15, lq = lane >> 4;
    for (int mi = 0; mi < 4; mi++) {
        int p4 = p0 + wm * 64 + mi * 16 + lq * 4;
        for (int ni = 0; ni < 4; ni++) {
            int o = o0 + wn * 64 + ni * 16 + lr;
            size_t idx = ((size_t)b * CC + o) * PP + p4;
            float bias = proj_b[o];
            f32x4 xv = *(const f32x4*)(x + idx);
            f32x4 r;
            r[0] = acc[mi][ni][0] + bias + xv[0];
            r[1] = acc[mi][ni][1] + bias + xv[1];
            r[2] = acc[mi][ni][2] + bias + xv[2];
            r[3] = acc[mi][ni][3] + bias + xv[3];
            *(f32x4*)(out + idx) = r;
        }
    }
}

extern "C" void kernel_launch(void* const* d_in, const int* in_sizes, int n_in,
                              void* d_out, int out_size, void* d_ws, size_t ws_size,
                              hipStream_t stream) {
    const float* x      = (const float*)d_in[0];
    const float* norm_w = (const float*)d_in[1];
    const float* norm_b = (const float*)d_in[2];
    const float* qkv_w  = (const float*)d_in[3];
    const float* qkv_b  = (const float*)d_in[4];
    const float* proj_w = (const float*)d_in[5];
    const float* proj_b = (const float*)d_in[6];
    float* out = (float*)d_out;

    char* ws = (char*)d_ws;
    size_t off = 0;
    auto alloc = [&](size_t bytes) {
        void* p = ws + off;
        off += (bytes + 255) & ~(size_t)255;
        return p;
    };
    float* part = (float*)alloc(512 * 2 * sizeof(float));
    float* a_s  = (float*)alloc(BB * CC * sizeof(float));
    float* b_s  = (float*)alloc(BB * CC * sizeof(float));
    float* attn = (float*)alloc((size_t)BB * 64 * 16 * sizeof(float));
    unsigned short* Wqb = (unsigned short*)alloc((size_t)768 * 256 * 2);
    unsigned short* Wp  = (unsigned short*)alloc((size_t)BB * 256 * 256 * 2);
    unsigned short* xnT = (unsigned short*)alloc((size_t)BB * PP * CC * 2);
    unsigned short* qk  = (unsigned short*)alloc((size_t)BB * 512 * PP * 2);
    unsigned short* vT  = (unsigned short*)alloc((size_t)BB * PP * CC * 2);

    gn_partial_k<<<512, 256, 0, stream>>>(x, part);
    gn_final_k<<<1, 128, 0, stream>>>(part, norm_w, norm_b, a_s, b_s);
    cvt_bf16_k<<<768, 256, 0, stream>>>(qkv_w, Wqb, 768 * 256);
    xnt_k<<<4096, 256, 0, stream>>>(x, a_s, b_s, xnT);
    qkv_gemm_k<<<16 * 6 * 32, 256, 0, stream>>>(Wqb, xnT, qkv_b, qk, vT);
    scores_k<<<16 * 64, 256, 0, stream>>>(qk, attn);
    make_wp_k<<<16 * 256, 256, 0, stream>>>(proj_w, attn, Wp);
    final_gemm_k<<<16 * 2 * 32, 256, 0, stream>>>(Wp, vT, proj_b, x, out);
}

// Round 3
// 270.180 us; speedup vs baseline: 1.0832x; 1.0493x over previous
//
#include <hip/hip_runtime.h>
#include <stdint.h>

#define BB 16
#define CC 256
#define PP 4096

typedef __attribute__((ext_vector_type(4))) float f32x4;
typedef __attribute__((ext_vector_type(8))) short bf16x8;

static __device__ __forceinline__ float bf2f(unsigned short u) {
    union { uint32_t i; float f; } w; w.i = ((uint32_t)u) << 16; return w.f;
}
static __device__ __forceinline__ unsigned short f2bf(float f) {
    union { float f; uint32_t i; } w; w.f = f;
    uint32_t u = w.i;
    uint32_t r = u + 0x7FFFu + ((u >> 16) & 1u);
    return (unsigned short)(r >> 16);
}
static __device__ __forceinline__ float dot4(f32x4 a, f32x4 b) {
    return a.x * b.x + a.y * b.y + a.z * b.z + a.w * b.w;
}

// async global -> LDS, 16 bytes per lane
static __device__ __forceinline__ void gl2lds16(const void* g, void* l) {
    __builtin_amdgcn_global_load_lds(
        (const __attribute__((address_space(1))) void*)g,
        (__attribute__((address_space(3))) void*)l, 16, 0, 0);
}

// ---------------- GroupNorm stats: per-channel sums ----------------
__global__ void gn_partial_k(const float* __restrict__ x, float* __restrict__ Sx,
                             float* __restrict__ Sxx) {
    int ch0 = blockIdx.x * 8;
    int t = threadIdx.x;
    int lc = t >> 5, l32 = t & 31;
    int ch = ch0 + lc;
    const f32x4* v = (const f32x4*)(x + (size_t)ch * PP);
    float s = 0.f, ss = 0.f;
    for (int i = l32; i < PP / 4; i += 32) {
        f32x4 tv = v[i];
        s  += tv.x + tv.y + tv.z + tv.w;
        ss += tv.x * tv.x + tv.y * tv.y + tv.z * tv.z + tv.w * tv.w;
    }
    for (int off = 16; off > 0; off >>= 1) {
        s  += __shfl_down(s, off, 32);
        ss += __shfl_down(ss, off, 32);
    }
    if (l32 == 0) { Sx[ch] = s; Sxx[ch] = ss; }
}

// per-(b,c): a (scale), sh (shift), s_vec = sum_p xn[b,c,p]
__global__ void gn_final_k(const float* __restrict__ Sx, const float* __restrict__ Sxx,
                           const float* __restrict__ nw, const float* __restrict__ nb,
                           float* __restrict__ a_s, float* __restrict__ b_s,
                           float* __restrict__ s_vec) {
    int b = blockIdx.x, c = threadIdx.x;
    __shared__ float lsx[256], lsxx[256];
    float mySx = Sx[b * CC + c];
    lsx[c] = mySx; lsxx[c] = Sxx[b * CC + c];
    __syncthreads();
    int g0 = (c >> 5) << 5;
    float S = 0.f, SS = 0.f;
    for (int j = 0; j < 32; j++) { S += lsx[g0 + j]; SS += lsxx[g0 + j]; }
    const float inv = 1.0f / 131072.0f;
    float mean = S * inv;
    float var = SS * inv - mean * mean;
    float rstd = rsqrtf(var + 1e-5f);
    float w = nw[c];
    float a = rstd * w;
    float sh = nb[c] - mean * rstd * w;
    a_s[b * CC + c] = a;
    b_s[b * CC + c] = sh;
    s_vec[b * CC + c] = a * mySx + 4096.0f * sh;
}

// ---------------- weight fp32 -> bf16 (all 768 qkv rows) ----------------
__global__ void cvt_bf16_k(const float* __restrict__ in, unsigned short* __restrict__ out, int n) {
    int i = blockIdx.x * 256 + threadIdx.x;
    if (i < n) out[i] = f2bf(in[i]);
}

// ---------------- normalize: write xnT[b][p][c] AND xnC[b][c][p] (bf16) ------------
__global__ void xnt_k(const float* __restrict__ x, const float* __restrict__ a_s,
                      const float* __restrict__ b_s, unsigned short* __restrict__ xnT,
                      unsigned short* __restrict__ xnC) {
    int pt = blockIdx.x & 63, ct = (blockIdx.x >> 6) & 3, b = blockIdx.x >> 8;
    int c0 = ct * 64, p0 = pt * 64;
    __shared__ unsigned short T[64][66];
    int t = threadIdx.x;
    int cl = t >> 4, pl4 = (t & 15) * 4;
    for (int i = 0; i < 4; i++) {
        int c = c0 + i * 16 + cl;
        float a = a_s[b * CC + c], sh = b_s[b * CC + c];
        f32x4 v = *(const f32x4*)(x + ((size_t)b * CC + c) * PP + p0 + pl4);
        ushort4 u;
        u.x = f2bf(a * v.x + sh);
        u.y = f2bf(a * v.y + sh);
        u.z = f2bf(a * v.z + sh);
        u.w = f2bf(a * v.w + sh);
        T[i * 16 + cl][pl4 + 0] = u.x;
        T[i * 16 + cl][pl4 + 1] = u.y;
        T[i * 16 + cl][pl4 + 2] = u.z;
        T[i * 16 + cl][pl4 + 3] = u.w;
        *(ushort4*)(xnC + ((size_t)b * CC + c) * PP + p0 + pl4) = u;
    }
    __syncthreads();
    int pl = t >> 2, c16 = (t & 3) * 16;
    union { unsigned short h[16]; uint4 u[2]; } buf;
    for (int j = 0; j < 16; j++) buf.h[j] = T[c16 + j][pl];
    unsigned short* dst = xnT + ((size_t)b * PP + p0 + pl) * CC + c0 + c16;
    *(uint4*)dst       = buf.u[0];
    *(uint4*)(dst + 8) = buf.u[1];
}

// ---------------- GEMM core: 128x128 tile, bf16 MFMA, DMA staging, XOR swizzle ----
// Rg rows -> D row (per-lane quad index). Cg rows -> D col (lane lr).
// LDS[r][slot] holds global k-chunk (slot ^ ((r>>1)&3)) -> bank-conflict-free b128 reads.
static __device__ __forceinline__ void gemm_core(const unsigned short* __restrict__ Rg,
                                                 const unsigned short* __restrict__ Cg,
                                                 int kLen, int rstride,
                                                 f32x4 (&acc)[4][4]) {
    __shared__ unsigned short Rs[128][32];
    __shared__ unsigned short Cs[128][32];
    int t = threadIdx.x;
    int lane = t & 63, wave = t >> 6;
    int wm = wave >> 1, wn = wave & 1;
    int lr = lane & 15, lq = lane >> 4;
    int srow = t >> 2;
    int ssl = (((t & 3) ^ ((t >> 3) & 3))) * 8;   // swizzled source k-offset (elements)
    int fsw = (lr >> 1) & 3;                       // fragment slot swizzle
    for (int mi = 0; mi < 4; mi++)
        for (int ni = 0; ni < 4; ni++) {
            acc[mi][ni][0] = 0.f; acc[mi][ni][1] = 0.f;
            acc[mi][ni][2] = 0.f; acc[mi][ni][3] = 0.f;
        }
    const unsigned short* gr0 = Rg + (size_t)srow * rstride + ssl;
    const unsigned short* gr1 = gr0 + (size_t)64 * rstride;
    const unsigned short* gc0 = Cg + (size_t)srow * rstride + ssl;
    const unsigned short* gc1 = gc0 + (size_t)64 * rstride;
    char* dr0 = (char*)&Rs[0][0] + t * 16;
    char* dr1 = dr0 + 4096;
    char* dc0 = (char*)&Cs[0][0] + t * 16;
    char* dc1 = dc0 + 4096;
    for (int k0 = 0; k0 < kLen; k0 += 32) {
        __syncthreads();
        gl2lds16(gr0 + k0, dr0);
        gl2lds16(gr1 + k0, dr1);
        gl2lds16(gc0 + k0, dc0);
        gl2lds16(gc1 + k0, dc1);
        __syncthreads();
        bf16x8 af[4], bfr[4];
        for (int mi = 0; mi < 4; mi++)
            af[mi]  = *(const bf16x8*)&Rs[wm * 64 + mi * 16 + lr][(lq ^ fsw) * 8];
        for (int ni = 0; ni < 4; ni++)
            bfr[ni] = *(const bf16x8*)&Cs[wn * 64 + ni * 16 + lr][(lq ^ fsw) * 8];
        for (int mi = 0; mi < 4; mi++)
            for (int ni = 0; ni < 4; ni++)
                acc[mi][ni] = __builtin_amdgcn_mfma_f32_16x16x32_bf16(af[mi], bfr[ni], acc[mi][ni], 0, 0, 0);
    }
}

// ---------------- v GEMM: vT[b][p][c] = Wv @ xn + bias ----------------
__global__ __launch_bounds__(256) void v_gemm_k(const unsigned short* __restrict__ Wvb,
                                                const unsigned short* __restrict__ xnT,
                                                const float* __restrict__ qkv_b,
                                                unsigned short* __restrict__ vT) {
    int nt = blockIdx.x & 31;
    int rest = blockIdx.x >> 5;
    int mt = rest & 1;
    int b  = rest >> 1;
    int c0 = mt * 128, p0 = nt * 128;
    f32x4 acc[4][4];
    gemm_core(Wvb + (size_t)c0 * 256, xnT + ((size_t)b * PP + p0) * 256, 256, 256, acc);
    int t = threadIdx.x, lane = t & 63, wave = t >> 6;
    int wm = wave >> 1, wn = wave & 1, lr = lane & 15, lq = lane >> 4;
    for (int mi = 0; mi < 4; mi++) {
        int c4 = c0 + wm * 64 + mi * 16 + lq * 4;
        f32x4 bias = *(const f32x4*)(qkv_b + 512 + c4);
        for (int ni = 0; ni < 4; ni++) {
            int p = p0 + wn * 64 + ni * 16 + lr;
            ushort4 u;
            u.x = f2bf(acc[mi][ni][0] + bias.x);
            u.y = f2bf(acc[mi][ni][1] + bias.y);
            u.z = f2bf(acc[mi][ni][2] + bias.z);
            u.w = f2bf(acc[mi][ni][3] + bias.w);
            *(ushort4*)(vT + ((size_t)b * PP + p) * CC + c4) = u;
        }
    }
}

// ---------------- Gram partials: Gpart[pc][b][c1][c2] = sum_p xn_c1 xn_c2 ----------
__global__ __launch_bounds__(256) void gram_k(const unsigned short* __restrict__ xnC,
                                              float* __restrict__ Gpart) {
    int pc  = blockIdx.x & 7;
    int t12 = (blockIdx.x >> 3) & 3;
    int b   = blockIdx.x >> 5;
    int t1 = (t12 >> 1) * 128;   // c1 -> col (lr)
    int t2 = (t12 & 1) * 128;    // c2 -> row (quad)
    f32x4 acc[4][4];
    gemm_core(xnC + ((size_t)b * CC + t2) * PP + pc * 512,
              xnC + ((size_t)b * CC + t1) * PP + pc * 512, 512, PP, acc);
    int t = threadIdx.x, lane = t & 63, wave = t >> 6;
    int wm = wave >> 1, wn = wave & 1, lr = lane & 15, lq = lane >> 4;
    float* dst = Gpart + ((size_t)(pc * 16 + b)) * 65536;
    for (int mi = 0; mi < 4; mi++) {
        int c2q = t2 + wm * 64 + mi * 16 + lq * 4;
        for (int ni = 0; ni < 4; ni++) {
            int c1 = t1 + wn * 64 + ni * 16 + lr;
            *(f32x4*)(dst + (size_t)c1 * 256 + c2q) = acc[mi][ni];
        }
    }
}

// ---------------- reduce partials, cast to bf16 ----------------
__global__ void greduce_k(const float* __restrict__ Gpart, unsigned short* __restrict__ Gb) {
    int i = blockIdx.x * 256 + threadIdx.x;   // over 16*65536
    float s = 0.f;
    for (int pc = 0; pc < 8; pc++) s += Gpart[(size_t)pc * 16 * 65536 + i];
    Gb[i] = f2bf(s);
}

// ---------------- U GEMM: UT[b][kr][c1] = sum_c2 G[c1,c2] * Wk[kr,c2] (fp32 out) ----
__global__ __launch_bounds__(256) void u_gemm_k(const unsigned short* __restrict__ Gb,
                                                const unsigned short* __restrict__ Wqkvb,
                                                float* __restrict__ UT) {
    int t12 = blockIdx.x & 3, b = blockIdx.x >> 2;
    int t1 = (t12 >> 1) * 128;   // c1 -> row (quad)
    int t2 = (t12 & 1) * 128;    // kr -> col (lr)
    f32x4 acc[4][4];
    gemm_core(Gb + ((size_t)b * 256 + t1) * 256,
              Wqkvb + (size_t)(256 + t2) * 256, 256, 256, acc);
    int t = threadIdx.x, lane = t & 63, wave = t >> 6;
    int wm = wave >> 1, wn = wave & 1, lr = lane & 15, lq = lane >> 4;
    for (int mi = 0; mi < 4; mi++) {
        int c1q = t1 + wm * 64 + mi * 16 + lq * 4;
        for (int ni = 0; ni < 4; ni++) {
            int kr = t2 + wn * 64 + ni * 16 + lr;
            *(f32x4*)(UT + ((size_t)b * 256 + kr) * 256 + c1q) = acc[mi][ni];
        }
    }
}

// ---------------- scores + softmax: attn[b][h][n][m] ----------------
// logits = 0.125*( wq_n . UT[m] + bq_n*(wk_m.s) + bk_m*(wq_n.s) + P*bq_n*bk_m )
__global__ void scoresfin_k(const float* __restrict__ qkv_w, const float* __restrict__ qkv_b,
                            const float* __restrict__ UT, const float* __restrict__ s_vec,
                            float* __restrict__ attn) {
    int h = blockIdx.x & 63, b = blockIdx.x >> 6;
    int l = threadIdx.x;          // 64 threads
    int c = l * 4;
    f32x4 sv = *(const f32x4*)(s_vec + b * CC + c);
    f32x4 wq[4], wk[4], ut[4];
    for (int n = 0; n < 4; n++) wq[n] = *(const f32x4*)(qkv_w + (size_t)(n * 64 + h) * 256 + c);
    for (int m = 0; m < 4; m++) wk[m] = *(const f32x4*)(qkv_w + (size_t)(256 + m * 64 + h) * 256 + c);
    for (int m = 0; m < 4; m++) ut[m] = *(const f32x4*)(UT + ((size_t)b * 256 + m * 64 + h) * 256 + c);
    float red[24];
    for (int n = 0; n < 4; n++)
        for (int m = 0; m < 4; m++) red[n * 4 + m] = dot4(wq[n], ut[m]);
    for (int n = 0; n < 4; n++) red[16 + n] = dot4(wq[n], sv);
    for (int m = 0; m < 4; m++) red[20 + m] = dot4(wk[m], sv);
    #pragma unroll
    for (int i = 0; i < 24; i++)
        for (int off = 32; off > 0; off >>= 1)
            red[i] += __shfl_xor(red[i], off);
    __shared__ float sred[24];
    if (l == 0)
        for (int i = 0; i < 24; i++) sred[i] = red[i];
    __syncthreads();
    if (l < 4) {
        int n = l;
        float bq = qkv_b[n * 64 + h];
        float dqn = sred[16 + n];
        float lg[4];
        for (int m = 0; m < 4; m++) {
            float bk = qkv_b[256 + m * 64 + h];
            lg[m] = 0.125f * (sred[n * 4 + m] + bq * sred[20 + m] + bk * dqn + 4096.0f * bq * bk);
        }
        float mx = fmaxf(fmaxf(lg[0], lg[1]), fmaxf(lg[2], lg[3]));
        float e0 = expf(lg[0] - mx), e1 = expf(lg[1] - mx);
        float e2 = expf(lg[2] - mx), e3 = expf(lg[3] - mx);
        float inv = 1.0f / (e0 + e1 + e2 + e3);
        float* dst = attn + ((size_t)(b * 64 + h) * 4 + n) * 4;
        dst[0] = e0 * inv; dst[1] = e1 * inv; dst[2] = e2 * inv; dst[3] = e3 * inv;
    }
}

// ---------------- fold attn into proj weights: Wp[b][o][m*64+hh] bf16 ----------------
__global__ void make_wp_k(const float* __restrict__ proj_w, const float* __restrict__ attn,
                          unsigned short* __restrict__ Wp) {
    int t = threadIdx.x;
    int o = blockIdx.x & 255, b = blockIdx.x >> 8;
    int m = t >> 6, hh = t & 63;
    float s = 0.f;
    for (int n = 0; n < 4; n++)
        s += proj_w[o * 256 + n * 64 + hh] * attn[((size_t)(b * 64 + hh) * 4 + n) * 4 + m];
    Wp[((size_t)b * 256 + o) * 256 + t] = f2bf(s);
}

// ---------------- final GEMM: out = Wp_b @ v + proj_b + x (p on row quad) ----------
__global__ __launch_bounds__(256) void final_gemm_k(const unsigned short* __restrict__ Wp,
                                                    const unsigned short* __restrict__ vT,
                                                    const float* __restrict__ proj_b,
                                                    const float* __restrict__ x,
                                                    float* __restrict__ out) {
    int nt = blockIdx.x & 31;
    int rest = blockIdx.x >> 5;
    int mt = rest & 1;
    int b  = rest >> 1;
    int o0 = mt * 128, p0 = nt * 128;
    f32x4 acc[4][4];
    gemm_core(vT + ((size_t)b * PP + p0) * 256, Wp + ((size_t)b * 256 + o0) * 256, 256, 256, acc);
    int t = threadIdx.x, lane = t & 63, wave = t >> 6;
    int wm = wave >> 1, wn = wave & 1, lr = lane & 15, lq = lane >> 4;
    for (int mi = 0; mi < 4; mi++) {
        int p4 = p0 + wm * 64 + mi * 16 + lq * 4;
        for (int ni = 0; ni < 4; ni++) {
            int o = o0 + wn * 64 + ni * 16 + lr;
            size_t idx = ((size_t)b * CC + o) * PP + p4;
            float bias = proj_b[o];
            f32x4 xv = *(const f32x4*)(x + idx);
            f32x4 r;
            r[0] = acc[mi][ni][0] + bias + xv[0];
            r[1] = acc[mi][ni][1] + bias + xv[1];
            r[2] = acc[mi][ni][2] + bias + xv[2];
            r[3] = acc[mi][ni][3] + bias + xv[3];
            *(f32x4*)(out + idx) = r;
        }
    }
}

extern "C" void kernel_launch(void* const* d_in, const int* in_sizes, int n_in,
                              void* d_out, int out_size, void* d_ws, size_t ws_size,
                              hipStream_t stream) {
    const float* x      = (const float*)d_in[0];
    const float* norm_w = (const float*)d_in[1];
    const float* norm_b = (const float*)d_in[2];
    const float* qkv_w  = (const float*)d_in[3];
    const float* qkv_b  = (const float*)d_in[4];
    const float* proj_w = (const float*)d_in[5];
    const float* proj_b = (const float*)d_in[6];
    float* out = (float*)d_out;

    char* ws = (char*)d_ws;
    size_t off = 0;
    auto alloc = [&](size_t bytes) {
        void* p = ws + off;
        off += (bytes + 255) & ~(size_t)255;
        return p;
    };
    float* Sx    = (float*)alloc(BB * CC * sizeof(float));
    float* Sxx   = (float*)alloc(BB * CC * sizeof(float));
    float* a_s   = (float*)alloc(BB * CC * sizeof(float));
    float* b_s   = (float*)alloc(BB * CC * sizeof(float));
    float* s_vec = (float*)alloc(BB * CC * sizeof(float));
    float* attn  = (float*)alloc((size_t)BB * 64 * 16 * sizeof(float));
    unsigned short* Wqkvb = (unsigned short*)alloc((size_t)768 * 256 * 2);
    unsigned short* Wp    = (unsigned short*)alloc((size_t)BB * 256 * 256 * 2);
    unsigned short* Gb    = (unsigned short*)alloc((size_t)BB * 65536 * 2);
    float*          UT    = (float*)alloc((size_t)BB * 65536 * 4);
    float*          Gpart = (float*)alloc((size_t)8 * BB * 65536 * 4);
    unsigned short* xnT   = (unsigned short*)alloc((size_t)BB * PP * CC * 2);
    unsigned short* xnC   = (unsigned short*)alloc((size_t)BB * PP * CC * 2);
    unsigned short* vT    = (unsigned short*)alloc((size_t)BB * PP * CC * 2);

    gn_partial_k<<<BB * CC / 8, 256, 0, stream>>>(x, Sx, Sxx);
    gn_final_k<<<BB, 256, 0, stream>>>(Sx, Sxx, norm_w, norm_b, a_s, b_s, s_vec);
    cvt_bf16_k<<<768, 256, 0, stream>>>(qkv_w, Wqkvb, 768 * 256);
    xnt_k<<<4096, 256, 0, stream>>>(x, a_s, b_s, xnT, xnC);
    v_gemm_k<<<BB * 2 * 32, 256, 0, stream>>>(Wqkvb + 512 * 256, xnT, qkv_b, vT);
    gram_k<<<BB * 4 * 8, 256, 0, stream>>>(xnC, Gpart);
    greduce_k<<<BB * 65536 / 256, 256, 0, stream>>>(Gpart, Gb);
    u_gemm_k<<<BB * 4, 256, 0, stream>>>(Gb, Wqkvb, UT);
    scoresfin_k<<<BB * 64, 64, 0, stream>>>(qkv_w, qkv_b, UT, s_vec, attn);
    make_wp_k<<<BB * 256, 256, 0, stream>>>(proj_w, attn, Wp);
    final_gemm_k<<<BB * 2 * 32, 256, 0, stream>>>(Wp, vT, proj_b, x, out);
}

// Round 5
// 242.225 us; speedup vs baseline: 1.2083x; 1.1154x over previous
//
#include <hip/hip_runtime.h>
#include <stdint.h>

#define BB 16
#define CC 256
#define PP 4096

typedef __attribute__((ext_vector_type(4))) float f32x4;
typedef __attribute__((ext_vector_type(8))) short bf16x8;

static __device__ __forceinline__ float bf2f(unsigned short u) {
    union { uint32_t i; float f; } w; w.i = ((uint32_t)u) << 16; return w.f;
}
static __device__ __forceinline__ unsigned short f2bf(float f) {
    union { float f; uint32_t i; } w; w.f = f;
    uint32_t u = w.i;
    uint32_t r = u + 0x7FFFu + ((u >> 16) & 1u);
    return (unsigned short)(r >> 16);
}
static __device__ __forceinline__ float dot4(f32x4 a, f32x4 b) {
    return a.x * b.x + a.y * b.y + a.z * b.z + a.w * b.w;
}

// ---------------- GroupNorm stats: per-channel sums ----------------
__global__ void gn_partial_k(const float* __restrict__ x, float* __restrict__ Sx,
                             float* __restrict__ Sxx) {
    int ch0 = blockIdx.x * 8;
    int t = threadIdx.x;
    int lc = t >> 5, l32 = t & 31;
    int ch = ch0 + lc;
    const f32x4* v = (const f32x4*)(x + (size_t)ch * PP);
    float s = 0.f, ss = 0.f;
    for (int i = l32; i < PP / 4; i += 32) {
        f32x4 tv = v[i];
        s  += tv.x + tv.y + tv.z + tv.w;
        ss += tv.x * tv.x + tv.y * tv.y + tv.z * tv.z + tv.w * tv.w;
    }
    for (int off = 16; off > 0; off >>= 1) {
        s  += __shfl_down(s, off, 32);
        ss += __shfl_down(ss, off, 32);
    }
    if (l32 == 0) { Sx[ch] = s; Sxx[ch] = ss; }
}

// per-(b,c): a (scale), sh (shift), s_vec = sum_p xn[b,c,p]
__global__ void gn_final_k(const float* __restrict__ Sx, const float* __restrict__ Sxx,
                           const float* __restrict__ nw, const float* __restrict__ nb,
                           float* __restrict__ a_s, float* __restrict__ b_s,
                           float* __restrict__ s_vec) {
    int b = blockIdx.x, c = threadIdx.x;
    __shared__ float lsx[256], lsxx[256];
    float mySx = Sx[b * CC + c];
    lsx[c] = mySx; lsxx[c] = Sxx[b * CC + c];
    __syncthreads();
    int g0 = (c >> 5) << 5;
    float S = 0.f, SS = 0.f;
    for (int j = 0; j < 32; j++) { S += lsx[g0 + j]; SS += lsxx[g0 + j]; }
    const float inv = 1.0f / 131072.0f;
    float mean = S * inv;
    float var = SS * inv - mean * mean;
    float rstd = rsqrtf(var + 1e-5f);
    float w = nw[c];
    float a = rstd * w;
    float sh = nb[c] - mean * rstd * w;
    a_s[b * CC + c] = a;
    b_s[b * CC + c] = sh;
    s_vec[b * CC + c] = a * mySx + 4096.0f * sh;
}

// ---------------- weight fp32 -> bf16 (all 768 qkv rows) ----------------
__global__ void cvt_bf16_k(const float* __restrict__ in, unsigned short* __restrict__ out, int n) {
    int i = blockIdx.x * 256 + threadIdx.x;
    if (i < n) out[i] = f2bf(in[i]);
}

// ---------------- Wv transpose: WvT[c2][c1] = Wv[c1][c2], bf16 ----------------
__global__ void wvt_k(const float* __restrict__ Wv, unsigned short* __restrict__ WvT) {
    int tc1 = blockIdx.x & 3, tc2 = blockIdx.x >> 2;   // 4x4 tiles of 64
    int c1_0 = tc1 * 64, c2_0 = tc2 * 64;
    __shared__ unsigned short T[64][65];
    int t = threadIdx.x;
    int r = t >> 2, q = (t & 3) * 16;
    for (int j = 0; j < 4; j++) {
        f32x4 v = *(const f32x4*)(Wv + (size_t)(c1_0 + r) * 256 + c2_0 + q + j * 4);
        T[r][q + j * 4 + 0] = f2bf(v.x);
        T[r][q + j * 4 + 1] = f2bf(v.y);
        T[r][q + j * 4 + 2] = f2bf(v.z);
        T[r][q + j * 4 + 3] = f2bf(v.w);
    }
    __syncthreads();
    union { unsigned short h[16]; uint4 u[2]; } buf;
    for (int j = 0; j < 16; j++) buf.h[j] = T[q + j][r];
    unsigned short* dst = WvT + (size_t)(c2_0 + r) * 256 + c1_0 + q;
    *(uint4*)dst       = buf.u[0];
    *(uint4*)(dst + 8) = buf.u[1];
}

// ---------------- normalize: write xnT[b][p][c] AND xnC[b][c][p] (bf16) ------------
__global__ void xnt_k(const float* __restrict__ x, const float* __restrict__ a_s,
                      const float* __restrict__ b_s, unsigned short* __restrict__ xnT,
                      unsigned short* __restrict__ xnC) {
    int pt = blockIdx.x & 63, ct = (blockIdx.x >> 6) & 3, b = blockIdx.x >> 8;
    int c0 = ct * 64, p0 = pt * 64;
    __shared__ unsigned short T[64][66];
    int t = threadIdx.x;
    int cl = t >> 4, pl4 = (t & 15) * 4;
    for (int i = 0; i < 4; i++) {
        int c = c0 + i * 16 + cl;
        float a = a_s[b * CC + c], sh = b_s[b * CC + c];
        f32x4 v = *(const f32x4*)(x + ((size_t)b * CC + c) * PP + p0 + pl4);
        ushort4 u;
        u.x = f2bf(a * v.x + sh);
        u.y = f2bf(a * v.y + sh);
        u.z = f2bf(a * v.z + sh);
        u.w = f2bf(a * v.w + sh);
        T[i * 16 + cl][pl4 + 0] = u.x;
        T[i * 16 + cl][pl4 + 1] = u.y;
        T[i * 16 + cl][pl4 + 2] = u.z;
        T[i * 16 + cl][pl4 + 3] = u.w;
        *(ushort4*)(xnC + ((size_t)b * CC + c) * PP + p0 + pl4) = u;
    }
    __syncthreads();
    int pl = t >> 2, c16 = (t & 3) * 16;
    union { unsigned short h[16]; uint4 u[2]; } buf;
    for (int j = 0; j < 16; j++) buf.h[j] = T[c16 + j][pl];
    unsigned short* dst = xnT + ((size_t)b * PP + p0 + pl) * CC + c0 + c16;
    *(uint4*)dst       = buf.u[0];
    *(uint4*)(dst + 8) = buf.u[1];
}

// ---------------- GEMM core: 128x128 tile, bf16 MFMA, VGPR-staged software pipeline.
// Rg rows -> D row (per-lane quad index). Cg rows -> D col (lane lr).
// XOR swizzle keeps ds_read_b128 fragment loads bank-conflict-free (0 measured in R3).
static __device__ __forceinline__ void gemm_core(const unsigned short* __restrict__ Rg,
                                                 const unsigned short* __restrict__ Cg,
                                                 int kLen, int rstride,
                                                 f32x4 (&acc)[4][4]) {
    __shared__ unsigned short Rs[128][32];
    __shared__ unsigned short Cs[128][32];
    int t = threadIdx.x;
    int lane = t & 63, wave = t >> 6;
    int wm = wave >> 1, wn = wave & 1;
    int lr = lane & 15, lq = lane >> 4;
    int srow = t >> 2;
    int ssl = ((t & 3) ^ ((t >> 3) & 3)) * 8;   // swizzled source k-offset (elements)
    int sd  = (t & 3) * 8;                       // fixed LDS slot for this thread
    int fsw = (lr >> 1) & 3;                     // fragment slot swizzle
    for (int mi = 0; mi < 4; mi++)
        for (int ni = 0; ni < 4; ni++) {
            acc[mi][ni][0] = 0.f; acc[mi][ni][1] = 0.f;
            acc[mi][ni][2] = 0.f; acc[mi][ni][3] = 0.f;
        }
    const unsigned short* gr0 = Rg + (size_t)srow * rstride + ssl;
    const unsigned short* gr1 = gr0 + (size_t)64 * rstride;
    const unsigned short* gc0 = Cg + (size_t)srow * rstride + ssl;
    const unsigned short* gc1 = gc0 + (size_t)64 * rstride;
    uint4 ra0 = *(const uint4*)(gr0);
    uint4 ra1 = *(const uint4*)(gr1);
    uint4 rc0 = *(const uint4*)(gc0);
    uint4 rc1 = *(const uint4*)(gc1);
    for (int k0 = 0; k0 < kLen; k0 += 32) {
        __syncthreads();
        *(uint4*)&Rs[srow][sd]      = ra0;
        *(uint4*)&Rs[srow + 64][sd] = ra1;
        *(uint4*)&Cs[srow][sd]      = rc0;
        *(uint4*)&Cs[srow + 64][sd] = rc1;
        __syncthreads();
        int kn = k0 + 32;
        if (kn < kLen) {               // prefetch next chunk; in flight during MFMAs
            ra0 = *(const uint4*)(gr0 + kn);
            ra1 = *(const uint4*)(gr1 + kn);
            rc0 = *(const uint4*)(gc0 + kn);
            rc1 = *(const uint4*)(gc1 + kn);
        }
        bf16x8 af[4], bfr[4];
        for (int mi = 0; mi < 4; mi++)
            af[mi]  = *(const bf16x8*)&Rs[wm * 64 + mi * 16 + lr][(lq ^ fsw) * 8];
        for (int ni = 0; ni < 4; ni++)
            bfr[ni] = *(const bf16x8*)&Cs[wn * 64 + ni * 16 + lr][(lq ^ fsw) * 8];
        for (int mi = 0; mi < 4; mi++)
            for (int ni = 0; ni < 4; ni++)
                acc[mi][ni] = __builtin_amdgcn_mfma_f32_16x16x32_bf16(af[mi], bfr[ni], acc[mi][ni], 0, 0, 0);
    }
}

// ---------------- Gram partials: Gpart[pc][b][c1][c2] = sum_p xn_c1 xn_c2 ----------
__global__ __launch_bounds__(256, 3) void gram_k(const unsigned short* __restrict__ xnC,
                                                 float* __restrict__ Gpart) {
    int pc  = blockIdx.x & 7;
    int t12 = (blockIdx.x >> 3) & 3;
    int b   = blockIdx.x >> 5;
    int t1 = (t12 >> 1) * 128;   // c1 -> col (lr)
    int t2 = (t12 & 1) * 128;    // c2 -> row (quad)
    f32x4 acc[4][4];
    gemm_core(xnC + ((size_t)b * CC + t2) * PP + pc * 512,
              xnC + ((size_t)b * CC + t1) * PP + pc * 512, 512, PP, acc);
    int t = threadIdx.x, lane = t & 63, wave = t >> 6;
    int wm = wave >> 1, wn = wave & 1, lr = lane & 15, lq = lane >> 4;
    float* dst = Gpart + ((size_t)(pc * 16 + b)) * 65536;
    for (int mi = 0; mi < 4; mi++) {
        int c2q = t2 + wm * 64 + mi * 16 + lq * 4;
        for (int ni = 0; ni < 4; ni++) {
            int c1 = t1 + wn * 64 + ni * 16 + lr;
            *(f32x4*)(dst + (size_t)c1 * 256 + c2q) = acc[mi][ni];
        }
    }
}

// ---------------- reduce partials, cast to bf16 ----------------
__global__ void greduce_k(const float* __restrict__ Gpart, unsigned short* __restrict__ Gb) {
    int i = blockIdx.x * 256 + threadIdx.x;   // over 16*65536
    float s = 0.f;
    for (int pc = 0; pc < 8; pc++) s += Gpart[(size_t)pc * 16 * 65536 + i];
    Gb[i] = f2bf(s);
}

// ---------------- U GEMM: UT[b][kr][c1] = sum_c2 G[c1,c2] * Wk[kr,c2] (fp32 out) ----
__global__ __launch_bounds__(256, 3) void u_gemm_k(const unsigned short* __restrict__ Gb,
                                                   const unsigned short* __restrict__ Wqkvb,
                                                   float* __restrict__ UT) {
    int t12 = blockIdx.x & 3, b = blockIdx.x >> 2;
    int t1 = (t12 >> 1) * 128;   // c1 -> row (quad)
    int t2 = (t12 & 1) * 128;    // kr -> col (lr)
    f32x4 acc[4][4];
    gemm_core(Gb + ((size_t)b * 256 + t1) * 256,
              Wqkvb + (size_t)(256 + t2) * 256, 256, 256, acc);
    int t = threadIdx.x, lane = t & 63, wave = t >> 6;
    int wm = wave >> 1, wn = wave & 1, lr = lane & 15, lq = lane >> 4;
    for (int mi = 0; mi < 4; mi++) {
        int c1q = t1 + wm * 64 + mi * 16 + lq * 4;
        for (int ni = 0; ni < 4; ni++) {
            int kr = t2 + wn * 64 + ni * 16 + lr;
            *(f32x4*)(UT + ((size_t)b * 256 + kr) * 256 + c1q) = acc[mi][ni];
        }
    }
}

// ---------------- scores + softmax: attn[b][h][n][m] ----------------
__global__ void scoresfin_k(const float* __restrict__ qkv_w, const float* __restrict__ qkv_b,
                            const float* __restrict__ UT, const float* __restrict__ s_vec,
                            float* __restrict__ attn) {
    int h = blockIdx.x & 63, b = blockIdx.x >> 6;
    int l = threadIdx.x;          // 64 threads
    int c = l * 4;
    f32x4 sv = *(const f32x4*)(s_vec + b * CC + c);
    f32x4 wq[4], wk[4], ut[4];
    for (int n = 0; n < 4; n++) wq[n] = *(const f32x4*)(qkv_w + (size_t)(n * 64 + h) * 256 + c);
    for (int m = 0; m < 4; m++) wk[m] = *(const f32x4*)(qkv_w + (size_t)(256 + m * 64 + h) * 256 + c);
    for (int m = 0; m < 4; m++) ut[m] = *(const f32x4*)(UT + ((size_t)b * 256 + m * 64 + h) * 256 + c);
    float red[24];
    for (int n = 0; n < 4; n++)
        for (int m = 0; m < 4; m++) red[n * 4 + m] = dot4(wq[n], ut[m]);
    for (int n = 0; n < 4; n++) red[16 + n] = dot4(wq[n], sv);
    for (int m = 0; m < 4; m++) red[20 + m] = dot4(wk[m], sv);
    #pragma unroll
    for (int i = 0; i < 24; i++)
        for (int off = 32; off > 0; off >>= 1)
            red[i] += __shfl_xor(red[i], off);
    __shared__ float sred[24];
    if (l == 0)
        for (int i = 0; i < 24; i++) sred[i] = red[i];
    __syncthreads();
    if (l < 4) {
        int n = l;
        float bq = qkv_b[n * 64 + h];
        float dqn = sred[16 + n];
        float lg[4];
        for (int m = 0; m < 4; m++) {
            float bk = qkv_b[256 + m * 64 + h];
            lg[m] = 0.125f * (sred[n * 4 + m] + bq * sred[20 + m] + bk * dqn + 4096.0f * bq * bk);
        }
        float mx = fmaxf(fmaxf(lg[0], lg[1]), fmaxf(lg[2], lg[3]));
        float e0 = expf(lg[0] - mx), e1 = expf(lg[1] - mx);
        float e2 = expf(lg[2] - mx), e3 = expf(lg[3] - mx);
        float inv = 1.0f / (e0 + e1 + e2 + e3);
        float* dst = attn + ((size_t)(b * 64 + h) * 4 + n) * 4;
        dst[0] = e0 * inv; dst[1] = e1 * inv; dst[2] = e2 * inv; dst[3] = e3 * inv;
    }
}

// ------- fold attn into proj weights: Wp[b][o][col] bf16, col = m*64+hh (v-channel)
// Also: bias2[b][o] = proj_b[o] + sum_col Wp[b][o][col]*bv[col]
__global__ void make_wp_k(const float* __restrict__ proj_w, const float* __restrict__ attn,
                          const float* __restrict__ qkv_b, const float* __restrict__ proj_b,
                          unsigned short* __restrict__ Wp, float* __restrict__ bias2) {
    int t = threadIdx.x;
    int o = blockIdx.x & 255, b = blockIdx.x >> 8;
    int m = t >> 6, hh = t & 63;
    float s = 0.f;
    for (int n = 0; n < 4; n++)
        s += proj_w[o * 256 + n * 64 + hh] * attn[((size_t)(b * 64 + hh) * 4 + n) * 4 + m];
    Wp[((size_t)b * 256 + o) * 256 + t] = f2bf(s);
    float contrib = s * qkv_b[512 + t];
    int lane = t & 63, wave = t >> 6;
    for (int off = 32; off > 0; off >>= 1) contrib += __shfl_down(contrib, off);
    __shared__ float red[4];
    if (lane == 0) red[wave] = contrib;
    __syncthreads();
    if (t == 0) bias2[b * 256 + o] = proj_b[o] + red[0] + red[1] + red[2] + red[3];
}

// ------- combined weight: Wc[b][o][c2] = sum_c1 Wp[b][o][c1] * Wv[c1][c2] (bf16) ----
// R = WvT (rows c2, k=c1 contiguous) -> quad; C = Wp (rows o, k=c1 contiguous) -> lr.
__global__ __launch_bounds__(256, 3) void make_wc_k(const unsigned short* __restrict__ WvT,
                                                    const unsigned short* __restrict__ Wp,
                                                    unsigned short* __restrict__ Wc) {
    int t12 = blockIdx.x & 3, b = blockIdx.x >> 2;
    int c20 = (t12 & 1) * 128;
    int o0  = (t12 >> 1) * 128;
    f32x4 acc[4][4];
    gemm_core(WvT + (size_t)c20 * 256, Wp + ((size_t)b * 256 + o0) * 256, 256, 256, acc);
    int t = threadIdx.x, lane = t & 63, wave = t >> 6;
    int wm = wave >> 1, wn = wave & 1, lr = lane & 15, lq = lane >> 4;
    for (int mi = 0; mi < 4; mi++) {
        int c2q = c20 + wm * 64 + mi * 16 + lq * 4;
        for (int ni = 0; ni < 4; ni++) {
            int o = o0 + wn * 64 + ni * 16 + lr;
            ushort4 u;
            u.x = f2bf(acc[mi][ni][0]);
            u.y = f2bf(acc[mi][ni][1]);
            u.z = f2bf(acc[mi][ni][2]);
            u.w = f2bf(acc[mi][ni][3]);
            *(ushort4*)(Wc + ((size_t)b * 256 + o) * 256 + c2q) = u;
        }
    }
}

// ---------------- final GEMM: out = Wc_b @ xn + bias2 + x (p on row quad) ----------
__global__ __launch_bounds__(256, 3) void final_gemm_k(const unsigned short* __restrict__ Wc,
                                                       const unsigned short* __restrict__ xnT,
                                                       const float* __restrict__ bias2,
                                                       const float* __restrict__ x,
                                                       float* __restrict__ out) {
    int nt = blockIdx.x & 31;
    int rest = blockIdx.x >> 5;
    int mt = rest & 1;
    int b  = rest >> 1;
    int o0 = mt * 128, p0 = nt * 128;
    f32x4 acc[4][4];
    gemm_core(xnT + ((size_t)b * PP + p0) * 256, Wc + ((size_t)b * 256 + o0) * 256, 256, 256, acc);
    int t = threadIdx.x, lane = t & 63, wave = t >> 6;
    int wm = wave >> 1, wn = wave & 1, lr = lane & 15, lq = lane >> 4;
    for (int mi = 0; mi < 4; mi++) {
        int p4 = p0 + wm * 64 + mi * 16 + lq * 4;
        for (int ni = 0; ni < 4; ni++) {
            int o = o0 + wn * 64 + ni * 16 + lr;
            size_t idx = ((size_t)b * CC + o) * PP + p4;
            float bias = bias2[b * CC + o];
            f32x4 xv = *(const f32x4*)(x + idx);
            f32x4 r;
            r[0] = acc[mi][ni][0] + bias + xv[0];
            r[1] = acc[mi][ni][1] + bias + xv[1];
            r[2] = acc[mi][ni][2] + bias + xv[2];
            r[3] = acc[mi][ni][3] + bias + xv[3];
            *(f32x4*)(out + idx) = r;
        }
    }
}

extern "C" void kernel_launch(void* const* d_in, const int* in_sizes, int n_in,
                              void* d_out, int out_size, void* d_ws, size_t ws_size,
                              hipStream_t stream) {
    const float* x      = (const float*)d_in[0];
    const float* norm_w = (const float*)d_in[1];
    const float* norm_b = (const float*)d_in[2];
    const float* qkv_w  = (const float*)d_in[3];
    const float* qkv_b  = (const float*)d_in[4];
    const float* proj_w = (const float*)d_in[5];
    const float* proj_b = (const float*)d_in[6];
    float* out = (float*)d_out;

    char* ws = (char*)d_ws;
    size_t off = 0;
    auto alloc = [&](size_t bytes) {
        void* p = ws + off;
        off += (bytes + 255) & ~(size_t)255;
        return p;
    };
    float* Sx    = (float*)alloc(BB * CC * sizeof(float));
    float* Sxx   = (float*)alloc(BB * CC * sizeof(float));
    float* a_s   = (float*)alloc(BB * CC * sizeof(float));
    float* b_s   = (float*)alloc(BB * CC * sizeof(float));
    float* s_vec = (float*)alloc(BB * CC * sizeof(float));
    float* attn  = (float*)alloc((size_t)BB * 64 * 16 * sizeof(float));
    float* bias2 = (float*)alloc(BB * CC * sizeof(float));
    unsigned short* Wqkvb = (unsigned short*)alloc((size_t)768 * 256 * 2);
    unsigned short* WvT   = (unsigned short*)alloc((size_t)256 * 256 * 2);
    unsigned short* Wp    = (unsigned short*)alloc((size_t)BB * 65536 * 2);
    unsigned short* Wc    = (unsigned short*)alloc((size_t)BB * 65536 * 2);
    unsigned short* Gb    = (unsigned short*)alloc((size_t)BB * 65536 * 2);
    float*          UT    = (float*)alloc((size_t)BB * 65536 * 4);
    float*          Gpart = (float*)alloc((size_t)8 * BB * 65536 * 4);
    unsigned short* xnT   = (unsigned short*)alloc((size_t)BB * PP * CC * 2);
    unsigned short* xnC   = (unsigned short*)alloc((size_t)BB * PP * CC * 2);

    gn_partial_k<<<BB * CC / 8, 256, 0, stream>>>(x, Sx, Sxx);
    gn_final_k<<<BB, 256, 0, stream>>>(Sx, Sxx, norm_w, norm_b, a_s, b_s, s_vec);
    cvt_bf16_k<<<768, 256, 0, stream>>>(qkv_w, Wqkvb, 768 * 256);
    wvt_k<<<16, 256, 0, stream>>>(qkv_w + (size_t)512 * 256, WvT);
    xnt_k<<<4096, 256, 0, stream>>>(x, a_s, b_s, xnT, xnC);
    gram_k<<<BB * 4 * 8, 256, 0, stream>>>(xnC, Gpart);
    greduce_k<<<BB * 65536 / 256, 256, 0, stream>>>(Gpart, Gb);
    u_gemm_k<<<BB * 4, 256, 0, stream>>>(Gb, Wqkvb, UT);
    scoresfin_k<<<BB * 64, 64, 0, stream>>>(qkv_w, qkv_b, UT, s_vec, attn);
    make_wp_k<<<BB * 256, 256, 0, stream>>>(proj_w, attn, qkv_b, proj_b, Wp, bias2);
    make_wc_k<<<BB * 4, 256, 0, stream>>>(WvT, Wp, Wc);
    final_gemm_k<<<BB * 2 * 32, 256, 0, stream>>>(Wc, xnT, bias2, x, out);
}